// Round 1
// baseline (310.117 us; speedup 1.0000x reference)
//
#include <hip/hip_runtime.h>

#define BB 16
#define CC 80
#define DD 1024
#define HW 196

// Kernel 0: transpose img [B, D, HW] -> imgT [B, HW, D] (workspace)
// One block per (b, hw) row; reads strided (L2-absorbed), writes coalesced.
__global__ __launch_bounds__(256) void transpose_k(const float* __restrict__ img,
                                                   float* __restrict__ imgT) {
    const int bhw = blockIdx.x;            // 0 .. B*HW-1
    const int b = bhw / HW;
    const int hw = bhw - b * HW;
    const float* src = img + (size_t)b * DD * HW + hw;
    float* dst = imgT + (size_t)bhw * DD;
    for (int d = threadIdx.x; d < DD; d += 256) {
        dst[d] = src[(size_t)d * HW];
    }
}

// Fused scores + softmax + pooling. One block per (b, c).
// Phase A: thread t (< HW) owns spatial position t, loops over d with
//          coalesced img reads and uniform (scalar) word/fa reads.
// Phase B: block softmax over the 196 lane-held scores via LDS.
// Phase C: threads re-map to d (4 values each), loop hw with coalesced
//          imgT reads (or strided img reads in the no-workspace fallback).
template <bool USE_T>
__global__ __launch_bounds__(256) void fused_k(const float* __restrict__ img,
                                               const float* __restrict__ imgT,
                                               const float* __restrict__ word,
                                               const float* __restrict__ fa,
                                               float* __restrict__ out) {
    const int bc = blockIdx.x;             // 0 .. B*C-1
    const int b = bc / CC;
    const int c = bc - b * CC;
    const int t = threadIdx.x;

    __shared__ float coef_s[HW];
    __shared__ float red_max[4];
    __shared__ float red_sum[4];

    // ---- Phase A: per-position score ----
    float score = -1e30f;
    if (t < HW) {
        const float* imgp = img + (size_t)b * DD * HW + t;
        const float* wp = word + (size_t)c * DD;
        float acc = 0.f;
#pragma unroll 4
        for (int d = 0; d < DD; ++d) {
            float x = imgp[(size_t)d * HW] * wp[d];
            // tanh(x) = 1 - 2/(e^{2x}+1): no NaN at +/- inf ends
            float e = __expf(2.f * x);
            float th = 1.f - 2.f / (e + 1.f);
            acc += th * fa[d];
        }
        score = acc;   // fc_a_b cancels in the softmax
    }

    // ---- Phase B: softmax over spatial positions (196 lanes) ----
    const int wv = t >> 6;
    float m = score;
#pragma unroll
    for (int off = 32; off >= 1; off >>= 1)
        m = fmaxf(m, __shfl_xor(m, off, 64));
    if ((t & 63) == 0) red_max[wv] = m;
    __syncthreads();
    m = fmaxf(fmaxf(red_max[0], red_max[1]), fmaxf(red_max[2], red_max[3]));

    float e = (t < HW) ? __expf(score - m) : 0.f;
    float s = e;
#pragma unroll
    for (int off = 32; off >= 1; off >>= 1)
        s += __shfl_xor(s, off, 64);
    if ((t & 63) == 0) red_sum[wv] = s;
    __syncthreads();
    s = red_sum[0] + red_sum[1] + red_sum[2] + red_sum[3];

    if (t < HW) coef_s[t] = e / s;
    __syncthreads();

    // ---- Phase C: attention-weighted pooling out[b,c,:] ----
    float a0 = 0.f, a1 = 0.f, a2 = 0.f, a3 = 0.f;
    if (USE_T) {
        const float* ip = imgT + (size_t)b * HW * DD + t;
        for (int hw = 0; hw < HW; ++hw) {
            const float cf = coef_s[hw];
            const float* row = ip + (size_t)hw * DD;
            a0 += cf * row[0];
            a1 += cf * row[256];
            a2 += cf * row[512];
            a3 += cf * row[768];
        }
    } else {
        const float* ip = img + (size_t)b * DD * HW;
        for (int hw = 0; hw < HW; ++hw) {
            const float cf = coef_s[hw];
            a0 += cf * ip[(size_t)(t      ) * HW + hw];
            a1 += cf * ip[(size_t)(t + 256) * HW + hw];
            a2 += cf * ip[(size_t)(t + 512) * HW + hw];
            a3 += cf * ip[(size_t)(t + 768) * HW + hw];
        }
    }
    float* op = out + ((size_t)b * CC + c) * DD + t;
    op[0]   = a0;
    op[256] = a1;
    op[512] = a2;
    op[768] = a3;
}

extern "C" void kernel_launch(void* const* d_in, const int* in_sizes, int n_in,
                              void* d_out, int out_size, void* d_ws, size_t ws_size,
                              hipStream_t stream) {
    // inputs: [0]=batch_size(int,1) [1]=img [2]=word [3]=fc_a_w [4]=fc_a_b
    const float* img  = (const float*)d_in[1];
    const float* word = (const float*)d_in[2];
    const float* fa   = (const float*)d_in[3];
    float* out = (float*)d_out;

    const size_t needT = (size_t)BB * HW * DD * sizeof(float);
    if (ws_size >= needT) {
        float* imgT = (float*)d_ws;
        transpose_k<<<BB * HW, 256, 0, stream>>>(img, imgT);
        fused_k<true><<<BB * CC, 256, 0, stream>>>(img, imgT, word, fa, out);
    } else {
        fused_k<false><<<BB * CC, 256, 0, stream>>>(img, nullptr, word, fa, out);
    }
}

// Round 2
// 198.568 us; speedup vs baseline: 1.5618x; 1.5618x over previous
//
#include <hip/hip_runtime.h>

#define BB 16
#define CC 80
#define DD 1024
#define HW 196
#define DCH 32           // d-chunk for scores kernel: grid 16 x 32 = 512 = 2 blocks/CU
#define LOG2E 1.44269504f

// ---------------- K0: prep ----------------
// wsc[c][d] = word[c][d] * 2*log2e  (so exp2(img*wsc) = e^{2*img*word})
// sums[b][c][hw] = 0 (atomic accumulation target)
__global__ __launch_bounds__(256) void prep_k(const float* __restrict__ word,
                                              float* __restrict__ wsc,
                                              float* __restrict__ sums) {
    int j = blockIdx.x * 256 + threadIdx.x;
    if (j < CC * DD) wsc[j] = word[j] * (2.f * LOG2E);
    if (j < BB * CC * HW) sums[j] = 0.f;
}

// ---------------- K1: scores ----------------
// Block (b, d-chunk). Thread = spatial position (196 of 256 active).
// img chunk held in 32 VGPRs, read ONCE; inner loop over all 80 classes with
// block-uniform wsc/fa (scalar loads). Accumulates P = sum_d fa[d]/(e^{2x}+1)
// per class via atomicAdd. score == const - 2P; const cancels in softmax.
__global__ __launch_bounds__(256) void scores_k(const float* __restrict__ img,
                                                const float* __restrict__ wsc,
                                                const float* __restrict__ fa,
                                                float* __restrict__ sums) {
    const int b  = blockIdx.x;          // 16
    const int d0 = blockIdx.y * DCH;    // 32 chunks
    const int t  = threadIdx.x;
    const bool act = (t < HW);
    const int hw = act ? t : (HW - 1);  // clamp: inactive lanes compute garbage, never write

    // load img[b, d0..d0+31, hw] into registers (coalesced across lanes)
    float iv[DCH];
    const float* ip = img + ((size_t)b * DD + d0) * HW + hw;
#pragma unroll
    for (int i = 0; i < DCH; ++i) iv[i] = ip[(size_t)i * HW];

    // fa chunk (block-uniform -> scalar regs)
    float fv[DCH];
    const float* fp = fa + d0;
#pragma unroll
    for (int i = 0; i < DCH; ++i) fv[i] = fp[i];

    for (int c = 0; c < CC; ++c) {
        const float* wp = wsc + (size_t)c * DD + d0;   // block-uniform -> s_load
        float p0 = 0.f, p1 = 0.f;
#pragma unroll
        for (int i = 0; i < DCH; i += 2) {
            float y0 = iv[i]     * wp[i];
            float y1 = iv[i + 1] * wp[i + 1];
            float e0 = __builtin_amdgcn_exp2f(y0);     // e^{2x}
            float e1 = __builtin_amdgcn_exp2f(y1);
            float r0 = __builtin_amdgcn_rcpf(e0 + 1.f);
            float r1 = __builtin_amdgcn_rcpf(e1 + 1.f);
            p0 = fmaf(fv[i],     r0, p0);
            p1 = fmaf(fv[i + 1], r1, p1);
        }
        if (act) atomicAdd(&sums[((size_t)b * CC + c) * HW + t], p0 + p1);
    }
}

// ---------------- K2: softmax over spatial positions ----------------
// Block per (b,c), 1 wave. score_log2 = -2*log2e*P; softmax via exp2.
__global__ __launch_bounds__(64) void softmax_k(const float* __restrict__ sums,
                                                float* __restrict__ coef) {
    const int bc = blockIdx.x;
    const int t  = threadIdx.x;
    const float* sp = sums + (size_t)bc * HW;
    const float SC = -2.f * LOG2E;

    float x0 = SC * sp[t];
    float x1 = SC * sp[t + 64];
    float x2 = SC * sp[t + 128];
    float x3 = (t < HW - 192) ? SC * sp[t + 192] : -3.4e38f;

    float m = fmaxf(fmaxf(x0, x1), fmaxf(x2, x3));
#pragma unroll
    for (int off = 32; off >= 1; off >>= 1) m = fmaxf(m, __shfl_xor(m, off, 64));

    float e0 = __builtin_amdgcn_exp2f(x0 - m);
    float e1 = __builtin_amdgcn_exp2f(x1 - m);
    float e2 = __builtin_amdgcn_exp2f(x2 - m);
    float e3 = (t < HW - 192) ? __builtin_amdgcn_exp2f(x3 - m) : 0.f;

    float s = e0 + e1 + e2 + e3;
#pragma unroll
    for (int off = 32; off >= 1; off >>= 1) s += __shfl_xor(s, off, 64);

    float inv = 1.f / s;
    float* cp = coef + (size_t)bc * HW;
    cp[t]       = e0 * inv;
    cp[t + 64]  = e1 * inv;
    cp[t + 128] = e2 * inv;
    if (t < HW - 192) cp[t + 192] = e3 * inv;
}

// ---------------- K3: pooling out[b,c,d] = sum_hw coef[b,c,hw]*img[b,d,hw] ----
// Block (b, d-tile of 64). img tile staged to LDS by a FLAT contiguous float4
// copy (rows [d][hw] are contiguous; stride 196 floats = 784 B is 16B-aligned
// and 196=4*49 (49 odd) -> b128 lane-spread hits all 32 banks uniformly).
// Wave w handles classes {w, w+4, ...}; lane = d offset; coef is wave-uniform
// (scalar loads).
__global__ __launch_bounds__(256) void pool_k(const float* __restrict__ img,
                                              const float* __restrict__ coef,
                                              float* __restrict__ out) {
    __shared__ float it[64 * HW];                 // 50176 B
    const int b  = blockIdx.x;                    // 16
    const int d0 = blockIdx.y * 64;               // 16 tiles
    const int t  = threadIdx.x;

    const float4* src = (const float4*)(img + ((size_t)b * DD + d0) * HW);
    float4* dst = (float4*)it;
    for (int j = t; j < 64 * HW / 4; j += 256) dst[j] = src[j];
    __syncthreads();

    const int w = t >> 6, l = t & 63;
    const float* irow = it + l * HW;              // 784B-aligned -> b128 ok
    const float* cb = coef + (size_t)b * CC * HW;

    for (int c = w; c < CC; c += 4) {
        const float* crow = cb + (size_t)c * HW;  // wave-uniform -> s_load
        float a0 = 0.f, a1 = 0.f, a2 = 0.f, a3 = 0.f;
#pragma unroll
        for (int h = 0; h < HW; h += 4) {
            float4 ivv = *(const float4*)(irow + h);
            a0 = fmaf(crow[h + 0], ivv.x, a0);
            a1 = fmaf(crow[h + 1], ivv.y, a1);
            a2 = fmaf(crow[h + 2], ivv.z, a2);
            a3 = fmaf(crow[h + 3], ivv.w, a3);
        }
        out[((size_t)b * CC + c) * DD + d0 + l] = (a0 + a1) + (a2 + a3);
    }
}

extern "C" void kernel_launch(void* const* d_in, const int* in_sizes, int n_in,
                              void* d_out, int out_size, void* d_ws, size_t ws_size,
                              hipStream_t stream) {
    // inputs: [0]=batch_size(int,1) [1]=img [2]=word [3]=fc_a_w [4]=fc_a_b
    const float* img  = (const float*)d_in[1];
    const float* word = (const float*)d_in[2];
    const float* fa   = (const float*)d_in[3];
    float* out = (float*)d_out;

    // workspace layout (floats): wsc[80*1024] | sums[16*80*196] | coef[16*80*196]
    float* wsc  = (float*)d_ws;
    float* sums = wsc + CC * DD;
    float* coef = sums + BB * CC * HW;

    const int prep_n = BB * CC * HW;  // 250880 > CC*DD
    prep_k<<<(prep_n + 255) / 256, 256, 0, stream>>>(word, wsc, sums);
    scores_k<<<dim3(BB, DD / DCH), 256, 0, stream>>>(img, wsc, fa, sums);
    softmax_k<<<BB * CC, 64, 0, stream>>>(sums, coef);
    pool_k<<<dim3(BB, DD / 64), 256, 0, stream>>>(img, coef, out);
}

// Round 3
// 166.076 us; speedup vs baseline: 1.8673x; 1.1956x over previous
//
#include <hip/hip_runtime.h>

#define BB 16
#define CC 80
#define DD 1024
#define HW 196
#define NSP (BB * HW)        // 3136 = 49 full waves, zero lane waste
#define NCH 8                // d-chunks of 128
#define DCH 128
#define NCQ 16               // class-groups
#define CPB 5                // classes per block
#define TWO_LOG2E 2.8853900817779268f

// ---------------- K1: scores ----------------
// Lane = flattened (b,hw) spatial slot (3136 = 49 exact waves).
// Block (g-tile, d-chunk of 128, c-group of 5). img chunk held in 32 VGPRs,
// reloaded per 32-d quarter; word/fa are block-uniform -> s_loads.
// P[c] = sum_d fa[d] / (e^{2 img w} + 1); score == K - 2P, K cancels in softmax.
// Each block exclusively owns partial[b][ch][c][hw] -> plain stores, no atomics.
__global__ __launch_bounds__(256) void scores_k(const float* __restrict__ img,
                                                const float* __restrict__ word,
                                                const float* __restrict__ fa,
                                                float* __restrict__ partial) {
    const int g = blockIdx.x * 256 + threadIdx.x;   // flattened (b,hw)
    if (g >= NSP) return;                           // wave-uniform exit (block 12, waves 1-3)
    const int b  = g / HW;
    const int hw = g - b * HW;
    const int d0 = blockIdx.y * DCH;
    const int c0 = blockIdx.z * CPB;

    const float* ip = img + ((size_t)b * DD + d0) * HW + hw;

    float p[CPB];
#pragma unroll
    for (int k = 0; k < CPB; ++k) p[k] = 0.f;

    for (int q = 0; q < DCH / 32; ++q) {            // 4 quarters of 32 d
        // img quarter -> 32 VGPRs, pre-scaled by 2*log2e so exp2(iv*w) = e^{2x}
        float iv[32];
#pragma unroll
        for (int i = 0; i < 32; ++i)
            iv[i] = ip[(size_t)(q * 32 + i) * HW] * TWO_LOG2E;

        const float* fp = fa + d0 + q * 32;          // uniform -> SGPRs
        float fv[32];
#pragma unroll
        for (int i = 0; i < 32; ++i) fv[i] = fp[i];

#pragma unroll
        for (int k = 0; k < CPB; ++k) {
            const float* wp = word + (size_t)(c0 + k) * DD + d0 + q * 32; // uniform -> s_load
            float p0 = 0.f, p1 = 0.f;
#pragma unroll
            for (int i = 0; i < 32; i += 2) {
                float y0 = iv[i]     * wp[i];
                float y1 = iv[i + 1] * wp[i + 1];
                float e0 = __builtin_amdgcn_exp2f(y0);      // e^{2x}
                float e1 = __builtin_amdgcn_exp2f(y1);
                float r0 = __builtin_amdgcn_rcpf(e0 + 1.f);
                float r1 = __builtin_amdgcn_rcpf(e1 + 1.f);
                p0 = fmaf(fv[i],     r0, p0);
                p1 = fmaf(fv[i + 1], r1, p1);
            }
            p[k] += p0 + p1;
        }
    }

#pragma unroll
    for (int k = 0; k < CPB; ++k)
        partial[(((size_t)b * NCH + blockIdx.y) * CC + (c0 + k)) * HW + hw] = p[k];
}

// ---------------- K2: chunk-reduce + softmax over spatial positions ----------------
// Block per (b,c), 256 threads (196 active). Sums the 8 d-chunk partials,
// then softmax of exp2(-2*log2e * P) over the 196 positions.
__global__ __launch_bounds__(256) void softmax_k(const float* __restrict__ partial,
                                                 float* __restrict__ coef) {
    const int bc = blockIdx.x;
    const int b = bc / CC, c = bc - b * CC;
    const int t = threadIdx.x;

    float P = 0.f;
    if (t < HW) {
#pragma unroll
        for (int ch = 0; ch < NCH; ++ch)
            P += partial[(((size_t)b * NCH + ch) * CC + c) * HW + t];
    }
    float x = (t < HW) ? (-TWO_LOG2E) * P : -3.4e38f;

    __shared__ float rmax[4], rsum[4];
    const int wv = t >> 6;

    float m = x;
#pragma unroll
    for (int off = 32; off >= 1; off >>= 1) m = fmaxf(m, __shfl_xor(m, off, 64));
    if ((t & 63) == 0) rmax[wv] = m;
    __syncthreads();
    m = fmaxf(fmaxf(rmax[0], rmax[1]), fmaxf(rmax[2], rmax[3]));

    float e = (t < HW) ? __builtin_amdgcn_exp2f(x - m) : 0.f;
    float s = e;
#pragma unroll
    for (int off = 32; off >= 1; off >>= 1) s += __shfl_xor(s, off, 64);
    if ((t & 63) == 0) rsum[wv] = s;
    __syncthreads();
    s = rsum[0] + rsum[1] + rsum[2] + rsum[3];

    if (t < HW) coef[((size_t)b * CC + c) * HW + t] = e * __builtin_amdgcn_rcpf(s);
}

// ---------------- K3: pooling out[b,c,d] = sum_hw coef[b,c,hw]*img[b,d,hw] ----
// Block (b, d-tile of 64), 512 threads = 8 waves. Flat float4 LDS staging
// (row stride 196 dwords == 4 mod 32 -> lane=d b128 reads are 16B-aligned and
// bank-tile perfectly). Wave w owns classes [10w, 10w+10): one ds_read_b128
// amortized over 40 FMAs; coef rows are wave-uniform -> s_load operands.
__global__ __launch_bounds__(512) void pool_k(const float* __restrict__ img,
                                              const float* __restrict__ coef,
                                              float* __restrict__ out) {
    __shared__ float it[64 * HW];                 // 50176 B
    const int b  = blockIdx.x;
    const int d0 = blockIdx.y * 64;
    const int t  = threadIdx.x;

    const float4* src = (const float4*)(img + ((size_t)b * DD + d0) * HW);
    float4* dst = (float4*)it;
    for (int j = t; j < 64 * HW / 4; j += 512) dst[j] = src[j];
    __syncthreads();

    const int w = t >> 6, l = t & 63;
    const float* irow = it + l * HW;
    const int cbase = w * 10;
    const float* cb = coef + ((size_t)b * CC + cbase) * HW;

    float acc[10];
#pragma unroll
    for (int k = 0; k < 10; ++k) acc[k] = 0.f;

    for (int h = 0; h < HW; h += 4) {
        float4 ivv = *(const float4*)(irow + h);
#pragma unroll
        for (int k = 0; k < 10; ++k) {
            const float* crow = cb + (size_t)k * HW + h;   // wave-uniform -> s_load
            acc[k] = fmaf(crow[0], ivv.x, acc[k]);
            acc[k] = fmaf(crow[1], ivv.y, acc[k]);
            acc[k] = fmaf(crow[2], ivv.z, acc[k]);
            acc[k] = fmaf(crow[3], ivv.w, acc[k]);
        }
    }

#pragma unroll
    for (int k = 0; k < 10; ++k)
        out[((size_t)b * CC + cbase + k) * DD + d0 + l] = acc[k];
}

extern "C" void kernel_launch(void* const* d_in, const int* in_sizes, int n_in,
                              void* d_out, int out_size, void* d_ws, size_t ws_size,
                              hipStream_t stream) {
    // inputs: [0]=batch_size(int,1) [1]=img [2]=word [3]=fc_a_w [4]=fc_a_b
    const float* img  = (const float*)d_in[1];
    const float* word = (const float*)d_in[2];
    const float* fa   = (const float*)d_in[3];
    float* out = (float*)d_out;

    // workspace (floats): partial[16][8][80][196] = 8.03MB | coef[16][80][196] = 10.04MB
    float* partial = (float*)d_ws;
    float* coef    = partial + (size_t)BB * NCH * CC * HW;

    scores_k<<<dim3((NSP + 255) / 256, NCH, NCQ), 256, 0, stream>>>(img, word, fa, partial);
    softmax_k<<<BB * CC, 256, 0, stream>>>(partial, coef);
    pool_k<<<dim3(BB, DD / 64), 512, 0, stream>>>(img, coef, out);
}

// Round 4
// 162.918 us; speedup vs baseline: 1.9035x; 1.0194x over previous
//
#include <hip/hip_runtime.h>

#define BB 16
#define CC 80
#define DD 1024
#define HW 196
#define NSP (BB * HW)        // 3136 = 49 full waves, zero lane waste
#define NCH 8                // d-chunks of 128
#define DCH 128
#define NCQ 16               // class-groups for scores
#define CPB 5                // classes per scores block
#define PCL 16               // classes per pool block
#define TWO_LOG2E 2.8853900817779268f

// ---------------- K1: scores ----------------
// Lane = flattened (b,hw). Block (g-tile, d-chunk 128, c-group 5).
// Software-pipelined: img quarter q+1 loads issue before computing quarter q
// (double register buffer ivA/ivB), so VMEM latency hides under the 5-class
// sigmoid compute. word/fa indexed by blockIdx-uniform bases -> s_loads.
// P[c] = sum_d fa[d] / (e^{2 img w} + 1); score == K - 2P, K cancels in softmax.
__global__ __launch_bounds__(256) void scores_k(const float* __restrict__ img,
                                                const float* __restrict__ word,
                                                const float* __restrict__ fa,
                                                float* __restrict__ partial) {
    const int g = blockIdx.x * 256 + threadIdx.x;   // flattened (b,hw)
    if (g >= NSP) return;                           // wave-uniform exit
    const int b  = g / HW;
    const int hw = g - b * HW;
    const int d0 = blockIdx.y * DCH;
    const int c0 = blockIdx.z * CPB;

    const float* ip = img + ((size_t)b * DD + d0) * HW + hw;

    float p[CPB];
#pragma unroll
    for (int k = 0; k < CPB; ++k) p[k] = 0.f;

    float ivA[32], ivB[32];

    auto loadq = [&](float* iv, int q) {
        const float* qp = ip + (size_t)q * 32 * HW;
#pragma unroll
        for (int i = 0; i < 32; ++i)
            iv[i] = qp[(size_t)i * HW] * TWO_LOG2E;   // pre-scale: exp2(iv*w)=e^{2x}
    };
    auto compute = [&](const float* iv, int q) {
        const float* fp = fa + d0 + q * 32;           // uniform -> SGPRs
#pragma unroll
        for (int k = 0; k < CPB; ++k) {
            const float* wp = word + (size_t)(c0 + k) * DD + d0 + q * 32; // uniform -> s_load
            float p0 = 0.f, p1 = 0.f;
#pragma unroll
            for (int i = 0; i < 32; i += 2) {
                float y0 = iv[i]     * wp[i];
                float y1 = iv[i + 1] * wp[i + 1];
                float e0 = __builtin_amdgcn_exp2f(y0);      // e^{2x}
                float e1 = __builtin_amdgcn_exp2f(y1);
                float r0 = __builtin_amdgcn_rcpf(e0 + 1.f);
                float r1 = __builtin_amdgcn_rcpf(e1 + 1.f);
                p0 = fmaf(fp[i],     r0, p0);
                p1 = fmaf(fp[i + 1], r1, p1);
            }
            p[k] += p0 + p1;
        }
    };

    loadq(ivA, 0);
    loadq(ivB, 1);          // in flight during compute of quarter 0
    compute(ivA, 0);
    loadq(ivA, 2);          // in flight during compute of quarter 1
    compute(ivB, 1);
    loadq(ivB, 3);          // in flight during compute of quarter 2
    compute(ivA, 2);
    compute(ivB, 3);

#pragma unroll
    for (int k = 0; k < CPB; ++k)
        partial[(((size_t)b * NCH + blockIdx.y) * CC + (c0 + k)) * HW + hw] = p[k];
}

// ---------------- K2: chunk-reduce + softmax over spatial positions ----------------
__global__ __launch_bounds__(256) void softmax_k(const float* __restrict__ partial,
                                                 float* __restrict__ coef) {
    const int bc = blockIdx.x;
    const int b = bc / CC, c = bc - b * CC;
    const int t = threadIdx.x;

    float P = 0.f;
    if (t < HW) {
#pragma unroll
        for (int ch = 0; ch < NCH; ++ch)
            P += partial[(((size_t)b * NCH + ch) * CC + c) * HW + t];
    }
    float x = (t < HW) ? (-TWO_LOG2E) * P : -3.4e38f;

    __shared__ float rmax[4], rsum[4];
    const int wv = t >> 6;

    float m = x;
#pragma unroll
    for (int off = 32; off >= 1; off >>= 1) m = fmaxf(m, __shfl_xor(m, off, 64));
    if ((t & 63) == 0) rmax[wv] = m;
    __syncthreads();
    m = fmaxf(fmaxf(rmax[0], rmax[1]), fmaxf(rmax[2], rmax[3]));

    float e = (t < HW) ? __builtin_amdgcn_exp2f(x - m) : 0.f;
    float s = e;
#pragma unroll
    for (int off = 32; off >= 1; off >>= 1) s += __shfl_xor(s, off, 64);
    if ((t & 63) == 0) rsum[wv] = s;
    __syncthreads();
    s = rsum[0] + rsum[1] + rsum[2] + rsum[3];

    if (t < HW) coef[((size_t)b * CC + c) * HW + t] = e * __builtin_amdgcn_rcpf(s);
}

// ---------------- K3: pooling out[b,c,d] = sum_hw coef[b,c,hw]*img[b,d,hw] ----
// Block (b, d-tile 64, c-group 16); grid 1280 x 256 thr = 5 waves/SIMD.
// BOTH img tile (50 KB) and coef tile (12.5 KB) staged to LDS with flat
// float4 copies (rows contiguous; dword row stride 196 == 4 mod 32 -> lane=d
// b128 reads tile all 32 banks, conflict-free). Thread: d = t&63, classes
// cq*4..cq*4+3 where cq = t>>6 -- coef reads are wave-uniform LDS addresses
// (broadcast, no VMEM gather storm like R2).
__global__ __launch_bounds__(256) void pool_k(const float* __restrict__ img,
                                              const float* __restrict__ coef,
                                              float* __restrict__ out) {
    __shared__ float it[64 * HW];                 // 50176 B
    __shared__ float ct[PCL * HW];                // 12544 B
    const int b  = blockIdx.x;
    const int d0 = blockIdx.y * 64;
    const int cg = blockIdx.z * PCL;
    const int t  = threadIdx.x;

    const float4* src = (const float4*)(img + ((size_t)b * DD + d0) * HW);
    float4* dst = (float4*)it;
    for (int j = t; j < 64 * HW / 4; j += 256) dst[j] = src[j];
    const float4* csrc = (const float4*)(coef + ((size_t)b * CC + cg) * HW);
    float4* cdst = (float4*)ct;
    for (int j = t; j < PCL * HW / 4; j += 256) cdst[j] = csrc[j];
    __syncthreads();

    const int d  = t & 63;
    const int cq = t >> 6;                        // 4 class-quads
    const float* irow = it + d * HW;
    const float* crow = ct + (cq * 4) * HW;

    float a0 = 0.f, a1 = 0.f, a2 = 0.f, a3 = 0.f;
    for (int h = 0; h < HW; h += 4) {
        float4 iv  = *(const float4*)(irow + h);
        float4 c0v = *(const float4*)(crow + h);
        float4 c1v = *(const float4*)(crow + HW + h);
        float4 c2v = *(const float4*)(crow + 2 * HW + h);
        float4 c3v = *(const float4*)(crow + 3 * HW + h);
        a0 = fmaf(iv.x, c0v.x, fmaf(iv.y, c0v.y, fmaf(iv.z, c0v.z, fmaf(iv.w, c0v.w, a0))));
        a1 = fmaf(iv.x, c1v.x, fmaf(iv.y, c1v.y, fmaf(iv.z, c1v.z, fmaf(iv.w, c1v.w, a1))));
        a2 = fmaf(iv.x, c2v.x, fmaf(iv.y, c2v.y, fmaf(iv.z, c2v.z, fmaf(iv.w, c2v.w, a2))));
        a3 = fmaf(iv.x, c3v.x, fmaf(iv.y, c3v.y, fmaf(iv.z, c3v.z, fmaf(iv.w, c3v.w, a3))));
    }

    float* op = out + ((size_t)b * CC + cg + cq * 4) * DD + d0 + d;
    op[0]      = a0;
    op[DD]     = a1;
    op[2 * DD] = a2;
    op[3 * DD] = a3;
}

extern "C" void kernel_launch(void* const* d_in, const int* in_sizes, int n_in,
                              void* d_out, int out_size, void* d_ws, size_t ws_size,
                              hipStream_t stream) {
    // inputs: [0]=batch_size(int,1) [1]=img [2]=word [3]=fc_a_w [4]=fc_a_b
    const float* img  = (const float*)d_in[1];
    const float* word = (const float*)d_in[2];
    const float* fa   = (const float*)d_in[3];
    float* out = (float*)d_out;

    // workspace (floats): partial[16][8][80][196] = 8.03MB | coef[16][80][196] = 2.51MB
    float* partial = (float*)d_ws;
    float* coef    = partial + (size_t)BB * NCH * CC * HW;

    scores_k<<<dim3((NSP + 255) / 256, NCH, NCQ), 256, 0, stream>>>(img, word, fa, partial);
    softmax_k<<<BB * CC, 256, 0, stream>>>(partial, coef);
    pool_k<<<dim3(BB, DD / 64, CC / PCL), 256, 0, stream>>>(img, coef, out);
}